// Round 3
// baseline (16937.794 us; speedup 1.0000x reference)
//
#include <hip/hip_runtime.h>
#include <stdint.h>

#define NN 100000
#define EE 3200000
#define DD 128
#define GG 64
#define CC 4
#define LLAYERS 3
#define KLIN 2
#define BN_EPS 1e-5f
#define MROWS 32

// x -> two f32 buffers (B pre-initialized for scatter self-term h + agg)
__global__ __launch_bounds__(256) void copy_dual(const float4* __restrict__ x,
                                                 float4* __restrict__ a,
                                                 float4* __restrict__ b, int n4){
  int i = blockIdx.x * 256 + threadIdx.x;
  if (i < n4) {
    float4 v = x[i];
    a[i] = v;
    b[i] = v;
  }
}

// one thread per (edge, 4-float chunk): o[dst] += h[src]
__global__ __launch_bounds__(256) void scatter_add_kernel(
    const float* __restrict__ h, float* __restrict__ o,
    const int* __restrict__ src, const int* __restrict__ dst){
  int t = blockIdx.x * 256 + threadIdx.x;
  int e = t >> 5, c = t & 31;
  if (e < EE) {
    int s = src[e], d = dst[e];
    float4 v = *(const float4*)(h + (size_t)s * DD + c * 4);
    float* p = o + (size_t)d * DD + c * 4;
    atomicAdd(p + 0, v.x);
    atomicAdd(p + 1, v.y);
    atomicAdd(p + 2, v.z);
    atomicAdd(p + 3, v.w);
  }
}

// O = relu((X @ W + bias - mean) * gamma/sqrt(var+eps) + beta); optional dual store
__global__ __launch_bounds__(256) void mlp_kernel(
    const float* __restrict__ X, float* __restrict__ O, float* __restrict__ O2,
    const float* __restrict__ W, const float* __restrict__ bias,
    const float* __restrict__ gamma, const float* __restrict__ beta,
    const float* __restrict__ mean, const float* __restrict__ var)
{
  __shared__ float Wt[32][DD];            // k-tile of W (rows k, cols j)
  __shared__ float Xs[MROWS][DD + 4];     // pad keeps float4 align, shifts banks
  __shared__ float scale_s[DD], shift_s[DD];

  const int tid = threadIdx.x;
  if (tid < DD) {
    float s = gamma[tid] * rsqrtf(var[tid] + BN_EPS);
    scale_s[tid] = s;
    shift_s[tid] = (bias[tid] - mean[tid]) * s + beta[tid];
  }
  const int r0 = blockIdx.x * MROWS;
  for (int t = tid; t < MROWS * 32; t += 256) {
    int row = t >> 5, c4 = t & 31;
    *(float4*)&Xs[row][c4 * 4] = *(const float4*)(X + (size_t)(r0 + row) * DD + c4 * 4);
  }

  const int rg = tid >> 5, cg = tid & 31;   // 8 row-groups x 32 col-groups
  float acc[4][4];
  #pragma unroll
  for (int i = 0; i < 4; ++i)
    #pragma unroll
    for (int j = 0; j < 4; ++j) acc[i][j] = 0.f;

  for (int kt = 0; kt < DD / 32; ++kt) {
    __syncthreads();   // protects Wt reuse (and covers Xs/scale on kt=0)
    for (int t = tid; t < 32 * 32; t += 256) {
      int row = t >> 5, c4 = t & 31;
      *(float4*)&Wt[row][c4 * 4] =
          *(const float4*)(W + (size_t)(kt * 32 + row) * DD + c4 * 4);
    }
    __syncthreads();
    #pragma unroll
    for (int kk = 0; kk < 32; ++kk) {
      const int k = kt * 32 + kk;
      float4 w = *(float4*)&Wt[kk][cg * 4];
      float x0 = Xs[rg*4+0][k];
      float x1 = Xs[rg*4+1][k];
      float x2 = Xs[rg*4+2][k];
      float x3 = Xs[rg*4+3][k];
      acc[0][0] += x0*w.x; acc[0][1] += x0*w.y; acc[0][2] += x0*w.z; acc[0][3] += x0*w.w;
      acc[1][0] += x1*w.x; acc[1][1] += x1*w.y; acc[1][2] += x1*w.z; acc[1][3] += x1*w.w;
      acc[2][0] += x2*w.x; acc[2][1] += x2*w.y; acc[2][2] += x2*w.z; acc[2][3] += x2*w.w;
      acc[3][0] += x3*w.x; acc[3][1] += x3*w.y; acc[3][2] += x3*w.z; acc[3][3] += x3*w.w;
    }
  }

  float sc[4], sh[4];
  #pragma unroll
  for (int j = 0; j < 4; ++j) { sc[j] = scale_s[cg*4+j]; sh[j] = shift_s[cg*4+j]; }
  #pragma unroll
  for (int i = 0; i < 4; ++i) {
    float4 o;
    o.x = fmaxf(acc[i][0]*sc[0]+sh[0], 0.f);
    o.y = fmaxf(acc[i][1]*sc[1]+sh[1], 0.f);
    o.z = fmaxf(acc[i][2]*sc[2]+sh[2], 0.f);
    o.w = fmaxf(acc[i][3]*sc[3]+sh[3], 0.f);
    size_t off = (size_t)(r0 + rg*4 + i) * DD + cg*4;
    *(float4*)(O + off) = o;
    if (O2) *(float4*)(O2 + off) = o;
  }
}

__global__ __launch_bounds__(256) void pool_init_kernel(float* __restrict__ pooled){
  int i = blockIdx.x*256 + threadIdx.x;
  if (i < GG*DD) pooled[i] = 0.f;   // valid identity: h is post-ReLU (>= 0)
}

__global__ __launch_bounds__(256) void pool_max_kernel(const float* __restrict__ h,
    const int* __restrict__ batch, float* __restrict__ pooled){
  int t = blockIdx.x*256 + threadIdx.x;
  int n = t >> 5, c = t & 31;
  if (n < NN) {
    int g = batch[n];
    float4 v = *(const float4*)(h + (size_t)n*DD + c*4);
    int* p = (int*)(pooled + (size_t)g*DD + c*4);
    atomicMax(p+0, __float_as_int(v.x));   // int compare == float compare for >= 0
    atomicMax(p+1, __float_as_int(v.y));
    atomicMax(p+2, __float_as_int(v.z));
    atomicMax(p+3, __float_as_int(v.w));
  }
}

__global__ __launch_bounds__(64) void classify_kernel(const float* __restrict__ pooled,
    const float* __restrict__ lw, const float* __restrict__ lb, float* __restrict__ out){
  int g = blockIdx.x, lane = threadIdx.x;
  float x0 = pooled[g*DD + lane];
  float x1 = pooled[g*DD + 64 + lane];
  float4 wA = *(const float4*)(lw + lane*4);        // lin_W[lane][0..3]
  float4 wB = *(const float4*)(lw + (lane+64)*4);   // lin_W[lane+64][0..3]
  float a0 = x0*wA.x + x1*wB.x;
  float a1 = x0*wA.y + x1*wB.y;
  float a2 = x0*wA.z + x1*wB.z;
  float a3 = x0*wA.w + x1*wB.w;
  #pragma unroll
  for (int off = 32; off > 0; off >>= 1) {
    a0 += __shfl_down(a0, off);
    a1 += __shfl_down(a1, off);
    a2 += __shfl_down(a2, off);
    a3 += __shfl_down(a3, off);
  }
  if (lane == 0) {
    float l0 = a0 + lb[0];
    float l1 = a1 + lb[1];
    float l2 = a2 + lb[2];
    float l3 = a3 + lb[3];
    float m = fmaxf(fmaxf(l0,l1), fmaxf(l2,l3));
    float s = expf(l0-m)+expf(l1-m)+expf(l2-m)+expf(l3-m);
    float lse = logf(s) + m;
    out[g*4+0] = l0 - lse;
    out[g*4+1] = l1 - lse;
    out[g*4+2] = l2 - lse;
    out[g*4+3] = l3 - lse;
  }
}

extern "C" void kernel_launch(void* const* d_in, const int* in_sizes, int n_in,
                              void* d_out, int out_size, void* d_ws, size_t ws_size,
                              hipStream_t stream) {
  const float* x     = (const float*)d_in[0];
  const int* ei      = (const int*)d_in[1];
  const int* batch   = (const int*)d_in[2];
  const float* Ws    = (const float*)d_in[3];
  const float* bs    = (const float*)d_in[4];
  const float* gammas= (const float*)d_in[5];
  const float* betas = (const float*)d_in[6];
  const float* means = (const float*)d_in[7];
  const float* vars  = (const float*)d_in[8];
  const float* lw    = (const float*)d_in[9];
  const float* lb    = (const float*)d_in[10];
  float* out = (float*)d_out;

  float* bufA = (float*)d_ws;
  float* bufB = bufA + (size_t)NN * DD;
  float* pooled = bufB + (size_t)NN * DD;

  const int* srcIdx = ei;
  const int* dstIdx = ei + EE;

  copy_dual<<<(NN*DD/4 + 255)/256, 256, 0, stream>>>(
      (const float4*)x, (float4*)bufA, (float4*)bufB, NN*DD/4);

  float* cur = bufA;
  float* oth = bufB;
  for (int l = 0; l < LLAYERS; ++l) {
    scatter_add_kernel<<<(EE*32)/256, 256, 0, stream>>>(cur, oth, srcIdx, dstIdx);
    const float* W0 = Ws + (size_t)(l*KLIN+0)*DD*DD;
    const float* W1 = Ws + (size_t)(l*KLIN+1)*DD*DD;
    int p0 = (l*KLIN+0)*DD, p1 = (l*KLIN+1)*DD;
    // oth = h+agg -> cur = mlp0(oth); then oth (and dup into cur) = mlp1(cur)
    mlp_kernel<<<NN/MROWS, 256, 0, stream>>>(oth, cur, nullptr,
        W0, bs+p0, gammas+p0, betas+p0, means+p0, vars+p0);
    mlp_kernel<<<NN/MROWS, 256, 0, stream>>>(cur, oth, cur,
        W1, bs+p1, gammas+p1, betas+p1, means+p1, vars+p1);
    float* t = cur; cur = oth; oth = t;   // both hold h; next scatter dst pre-init
  }
  pool_init_kernel<<<(GG*DD + 255)/256, 256, 0, stream>>>(pooled);
  pool_max_kernel<<<(NN*32 + 255)/256, 256, 0, stream>>>(cur, batch, pooled);
  classify_kernel<<<GG, 64, 0, stream>>>(pooled, lw, lb, out);
}

// Round 4
// 1961.757 us; speedup vs baseline: 8.6340x; 8.6340x over previous
//
#include <hip/hip_runtime.h>
#include <stdint.h>

#define NN 100000
#define EE 3200000
#define DD 128
#define GG 64
#define CC 4
#define LLAYERS 3
#define KLIN 2
#define BN_EPS 1e-5f
#define MROWS 32
#define SCAN_CHUNK 1024
#define NBLK ((NN + SCAN_CHUNK - 1) / SCAN_CHUNK)   // 98

// ---------------- CSR build (counting sort by dst) ----------------

__global__ __launch_bounds__(256) void hist_kernel(const int* __restrict__ dst,
                                                   int* __restrict__ deg){
  int e = blockIdx.x * 256 + threadIdx.x;
  if (e < EE) atomicAdd(&deg[dst[e]], 1);
}

// per-1024-chunk sums
__global__ __launch_bounds__(256) void scan_blocksum(const int* __restrict__ deg,
                                                     int* __restrict__ bsum){
  __shared__ int red[256];
  int b = blockIdx.x, t = threadIdx.x;
  int base = b * SCAN_CHUNK + t * 4;
  int s = 0;
  #pragma unroll
  for (int j = 0; j < 4; ++j) { int i = base + j; if (i < NN) s += deg[i]; }
  red[t] = s; __syncthreads();
  for (int off = 128; off > 0; off >>= 1) {
    if (t < off) red[t] += red[t + off];
    __syncthreads();
  }
  if (t == 0) bsum[b] = red[0];
}

__global__ __launch_bounds__(64) void scan_bsums(const int* __restrict__ bsum,
                                                 int* __restrict__ bofs){
  if (threadIdx.x == 0) {
    int run = 0;
    for (int i = 0; i < NBLK; ++i) { bofs[i] = run; run += bsum[i]; }
  }
}

__global__ __launch_bounds__(256) void scan_final(const int* __restrict__ deg,
                                                  const int* __restrict__ bofs,
                                                  int* __restrict__ row_start,
                                                  int* __restrict__ cursor){
  __shared__ int tsum[256];
  int b = blockIdx.x, t = threadIdx.x;
  int base = b * SCAN_CHUNK + t * 4;
  int d[4]; int s = 0;
  #pragma unroll
  for (int j = 0; j < 4; ++j) { int i = base + j; d[j] = (i < NN) ? deg[i] : 0; s += d[j]; }
  tsum[t] = s; __syncthreads();
  // Hillis-Steele inclusive scan over 256 thread sums
  for (int off = 1; off < 256; off <<= 1) {
    int v = (t >= off) ? tsum[t - off] : 0;
    __syncthreads();
    tsum[t] += v;
    __syncthreads();
  }
  int p = bofs[b] + tsum[t] - s;   // exclusive prefix for this thread's first elem
  #pragma unroll
  for (int j = 0; j < 4; ++j) {
    int i = base + j;
    if (i < NN) { row_start[i] = p; cursor[i] = p; p += d[j]; }
  }
  if (b == NBLK - 1 && t == 255) row_start[NN] = EE;
}

__global__ __launch_bounds__(256) void fill_kernel(const int* __restrict__ src,
                                                   const int* __restrict__ dst,
                                                   int* __restrict__ cursor,
                                                   int* __restrict__ sorted_src){
  int e = blockIdx.x * 256 + threadIdx.x;
  if (e < EE) {
    int pos = atomicAdd(&cursor[dst[e]], 1);
    sorted_src[pos] = src[e];
  }
}

// ---------------- per-node gather: o[n] = h[n] + sum_{s in N(n)} h[s] ----------------
// 8 nodes per 256-thread block; 32 lanes per node, float4 per lane (128 floats).
__global__ __launch_bounds__(256) void gather_kernel(const float4* __restrict__ h,
                                                     float4* __restrict__ o,
                                                     const int* __restrict__ row_start,
                                                     const int* __restrict__ sorted_src){
  int node = blockIdx.x * 8 + (threadIdx.x >> 5);
  int c = threadIdx.x & 31;
  if (node >= NN) return;
  float4 acc = h[(size_t)node * 32 + c];          // self term (eps=0)
  int beg = row_start[node], end = row_start[node + 1];
  for (int e = beg; e < end; ++e) {
    int s = sorted_src[e];
    float4 v = h[(size_t)s * 32 + c];
    acc.x += v.x; acc.y += v.y; acc.z += v.z; acc.w += v.w;
  }
  o[(size_t)node * 32 + c] = acc;
}

// ---------------- fused Linear + BN(eval) + ReLU ----------------
__global__ __launch_bounds__(256) void mlp_kernel(
    const float* __restrict__ X, float* __restrict__ O,
    const float* __restrict__ W, const float* __restrict__ bias,
    const float* __restrict__ gamma, const float* __restrict__ beta,
    const float* __restrict__ mean, const float* __restrict__ var)
{
  __shared__ float Wt[32][DD];            // k-tile of W (rows k, cols j)
  __shared__ float Xs[MROWS][DD + 4];     // pad keeps float4 align, shifts banks
  __shared__ float scale_s[DD], shift_s[DD];

  const int tid = threadIdx.x;
  if (tid < DD) {
    float s = gamma[tid] * rsqrtf(var[tid] + BN_EPS);
    scale_s[tid] = s;
    shift_s[tid] = (bias[tid] - mean[tid]) * s + beta[tid];
  }
  const int r0 = blockIdx.x * MROWS;
  for (int t = tid; t < MROWS * 32; t += 256) {
    int row = t >> 5, c4 = t & 31;
    *(float4*)&Xs[row][c4 * 4] = *(const float4*)(X + (size_t)(r0 + row) * DD + c4 * 4);
  }

  const int rg = tid >> 5, cg = tid & 31;   // 8 row-groups x 32 col-groups
  float acc[4][4];
  #pragma unroll
  for (int i = 0; i < 4; ++i)
    #pragma unroll
    for (int j = 0; j < 4; ++j) acc[i][j] = 0.f;

  for (int kt = 0; kt < DD / 32; ++kt) {
    __syncthreads();   // protects Wt reuse (and covers Xs/scale on kt=0)
    for (int t = tid; t < 32 * 32; t += 256) {
      int row = t >> 5, c4 = t & 31;
      *(float4*)&Wt[row][c4 * 4] =
          *(const float4*)(W + (size_t)(kt * 32 + row) * DD + c4 * 4);
    }
    __syncthreads();
    #pragma unroll
    for (int kk = 0; kk < 32; ++kk) {
      const int k = kt * 32 + kk;
      float4 w = *(float4*)&Wt[kk][cg * 4];
      float x0 = Xs[rg*4+0][k];
      float x1 = Xs[rg*4+1][k];
      float x2 = Xs[rg*4+2][k];
      float x3 = Xs[rg*4+3][k];
      acc[0][0] += x0*w.x; acc[0][1] += x0*w.y; acc[0][2] += x0*w.z; acc[0][3] += x0*w.w;
      acc[1][0] += x1*w.x; acc[1][1] += x1*w.y; acc[1][2] += x1*w.z; acc[1][3] += x1*w.w;
      acc[2][0] += x2*w.x; acc[2][1] += x2*w.y; acc[2][2] += x2*w.z; acc[2][3] += x2*w.w;
      acc[3][0] += x3*w.x; acc[3][1] += x3*w.y; acc[3][2] += x3*w.z; acc[3][3] += x3*w.w;
    }
  }

  float sc[4], sh[4];
  #pragma unroll
  for (int j = 0; j < 4; ++j) { sc[j] = scale_s[cg*4+j]; sh[j] = shift_s[cg*4+j]; }
  #pragma unroll
  for (int i = 0; i < 4; ++i) {
    float4 o;
    o.x = fmaxf(acc[i][0]*sc[0]+sh[0], 0.f);
    o.y = fmaxf(acc[i][1]*sc[1]+sh[1], 0.f);
    o.z = fmaxf(acc[i][2]*sc[2]+sh[2], 0.f);
    o.w = fmaxf(acc[i][3]*sc[3]+sh[3], 0.f);
    *(float4*)(O + (size_t)(r0 + rg*4 + i) * DD + cg*4) = o;
  }
}

// ---------------- pool + classify ----------------

__global__ __launch_bounds__(256) void pool_max_kernel(const float* __restrict__ h,
    const int* __restrict__ batch, float* __restrict__ pooled){
  int t = blockIdx.x*256 + threadIdx.x;
  int n = t >> 5, c = t & 31;
  if (n < NN) {
    int g = batch[n];
    float4 v = *(const float4*)(h + (size_t)n*DD + c*4);
    int* p = (int*)(pooled + (size_t)g*DD + c*4);
    atomicMax(p+0, __float_as_int(v.x));   // int compare == float compare for >= 0
    atomicMax(p+1, __float_as_int(v.y));
    atomicMax(p+2, __float_as_int(v.z));
    atomicMax(p+3, __float_as_int(v.w));
  }
}

__global__ __launch_bounds__(64) void classify_kernel(const float* __restrict__ pooled,
    const float* __restrict__ lw, const float* __restrict__ lb, float* __restrict__ out){
  int g = blockIdx.x, lane = threadIdx.x;
  float x0 = pooled[g*DD + lane];
  float x1 = pooled[g*DD + 64 + lane];
  float4 wA = *(const float4*)(lw + lane*4);        // lin_W[lane][0..3]
  float4 wB = *(const float4*)(lw + (lane+64)*4);   // lin_W[lane+64][0..3]
  float a0 = x0*wA.x + x1*wB.x;
  float a1 = x0*wA.y + x1*wB.y;
  float a2 = x0*wA.z + x1*wB.z;
  float a3 = x0*wA.w + x1*wB.w;
  #pragma unroll
  for (int off = 32; off > 0; off >>= 1) {
    a0 += __shfl_down(a0, off);
    a1 += __shfl_down(a1, off);
    a2 += __shfl_down(a2, off);
    a3 += __shfl_down(a3, off);
  }
  if (lane == 0) {
    float l0 = a0 + lb[0];
    float l1 = a1 + lb[1];
    float l2 = a2 + lb[2];
    float l3 = a3 + lb[3];
    float m = fmaxf(fmaxf(l0,l1), fmaxf(l2,l3));
    float s = expf(l0-m)+expf(l1-m)+expf(l2-m)+expf(l3-m);
    float lse = logf(s) + m;
    out[g*4+0] = l0 - lse;
    out[g*4+1] = l1 - lse;
    out[g*4+2] = l2 - lse;
    out[g*4+3] = l3 - lse;
  }
}

extern "C" void kernel_launch(void* const* d_in, const int* in_sizes, int n_in,
                              void* d_out, int out_size, void* d_ws, size_t ws_size,
                              hipStream_t stream) {
  const float* x     = (const float*)d_in[0];
  const int* ei      = (const int*)d_in[1];
  const int* batch   = (const int*)d_in[2];
  const float* Ws    = (const float*)d_in[3];
  const float* bs    = (const float*)d_in[4];
  const float* gammas= (const float*)d_in[5];
  const float* betas = (const float*)d_in[6];
  const float* means = (const float*)d_in[7];
  const float* vars  = (const float*)d_in[8];
  const float* lw    = (const float*)d_in[9];
  const float* lb    = (const float*)d_in[10];
  float* out = (float*)d_out;

  // workspace layout
  float* bufA   = (float*)d_ws;                         // N*D
  float* bufB   = bufA + (size_t)NN * DD;               // N*D
  float* pooled = bufB + (size_t)NN * DD;               // G*D
  int* deg        = (int*)(pooled + GG * DD);           // N (reused as cursor)
  int* row_start  = deg + NN;                           // N+1
  int* bsum       = row_start + NN + 1;                 // NBLK
  int* bofs       = bsum + NBLK;                        // NBLK
  int* sorted_src = bofs + NBLK + 2;                    // E  (keeps 16B align)

  const int* srcIdx = ei;
  const int* dstIdx = ei + EE;

  // ---- CSR build (once; graph is static across layers) ----
  hipMemsetAsync(deg, 0, NN * sizeof(int), stream);
  hist_kernel<<<(EE + 255)/256, 256, 0, stream>>>(dstIdx, deg);
  scan_blocksum<<<NBLK, 256, 0, stream>>>(deg, bsum);
  scan_bsums<<<1, 64, 0, stream>>>(bsum, bofs);
  scan_final<<<NBLK, 256, 0, stream>>>(deg, bofs, row_start, deg /*cursor*/);
  fill_kernel<<<(EE + 255)/256, 256, 0, stream>>>(srcIdx, dstIdx, deg, sorted_src);

  // ---- 3 GIN layers ----
  const float* hin = x;
  float* A = bufA;
  float* B = bufB;
  for (int l = 0; l < LLAYERS; ++l) {
    gather_kernel<<<(NN + 7)/8, 256, 0, stream>>>(
        (const float4*)hin, (float4*)B, row_start, sorted_src);
    const float* W0 = Ws + (size_t)(l*KLIN+0)*DD*DD;
    const float* W1 = Ws + (size_t)(l*KLIN+1)*DD*DD;
    int p0 = (l*KLIN+0)*DD, p1 = (l*KLIN+1)*DD;
    mlp_kernel<<<NN/MROWS, 256, 0, stream>>>(B, A,
        W0, bs+p0, gammas+p0, betas+p0, means+p0, vars+p0);
    mlp_kernel<<<NN/MROWS, 256, 0, stream>>>(A, B,
        W1, bs+p1, gammas+p1, betas+p1, means+p1, vars+p1);
    hin = B;                      // h now lives in B
    float* t = A; A = B; B = t;   // swap roles for next layer
  }
  // after loop, h == hin (points at the buffer holding final h)

  hipMemsetAsync(pooled, 0, GG * DD * sizeof(float), stream);  // identity: h >= 0
  pool_max_kernel<<<(NN*32 + 255)/256, 256, 0, stream>>>(hin, batch, pooled);
  classify_kernel<<<GG, 64, 0, stream>>>(pooled, lw, lb, out);
}

// Round 5
// 1589.792 us; speedup vs baseline: 10.6541x; 1.2340x over previous
//
#include <hip/hip_runtime.h>
#include <stdint.h>

#define NN 100000
#define EE 3200000
#define DD 128
#define GG 64
#define CC 4
#define LLAYERS 3
#define KLIN 2
#define BN_EPS 1e-5f
#define MROWS 32
#define SCAN_CHUNK 1024
#define NBLK ((NN + SCAN_CHUNK - 1) / SCAN_CHUNK)   // 98

// ---------------- CSR build (counting sort by dst) ----------------

__global__ __launch_bounds__(256) void hist_kernel(const int* __restrict__ dst,
                                                   int* __restrict__ deg){
  int e = blockIdx.x * 256 + threadIdx.x;
  if (e < EE) atomicAdd(&deg[dst[e]], 1);
}

// per-1024-chunk sums
__global__ __launch_bounds__(256) void scan_blocksum(const int* __restrict__ deg,
                                                     int* __restrict__ bsum){
  __shared__ int red[256];
  int b = blockIdx.x, t = threadIdx.x;
  int base = b * SCAN_CHUNK + t * 4;
  int s = 0;
  #pragma unroll
  for (int j = 0; j < 4; ++j) { int i = base + j; if (i < NN) s += deg[i]; }
  red[t] = s; __syncthreads();
  for (int off = 128; off > 0; off >>= 1) {
    if (t < off) red[t] += red[t + off];
    __syncthreads();
  }
  if (t == 0) bsum[b] = red[0];
}

__global__ __launch_bounds__(64) void scan_bsums(const int* __restrict__ bsum,
                                                 int* __restrict__ bofs){
  if (threadIdx.x == 0) {
    int run = 0;
    for (int i = 0; i < NBLK; ++i) { bofs[i] = run; run += bsum[i]; }
  }
}

__global__ __launch_bounds__(256) void scan_final(const int* __restrict__ deg,
                                                  const int* __restrict__ bofs,
                                                  int* __restrict__ row_start,
                                                  int* __restrict__ cursor){
  __shared__ int tsum[256];
  int b = blockIdx.x, t = threadIdx.x;
  int base = b * SCAN_CHUNK + t * 4;
  int d[4]; int s = 0;
  #pragma unroll
  for (int j = 0; j < 4; ++j) { int i = base + j; d[j] = (i < NN) ? deg[i] : 0; s += d[j]; }
  tsum[t] = s; __syncthreads();
  // Hillis-Steele inclusive scan over 256 thread sums
  for (int off = 1; off < 256; off <<= 1) {
    int v = (t >= off) ? tsum[t - off] : 0;
    __syncthreads();
    tsum[t] += v;
    __syncthreads();
  }
  int p = bofs[b] + tsum[t] - s;   // exclusive prefix for this thread's first elem
  #pragma unroll
  for (int j = 0; j < 4; ++j) {
    int i = base + j;
    if (i < NN) { row_start[i] = p; cursor[i] = p; p += d[j]; }
  }
  if (b == NBLK - 1 && t == 255) row_start[NN] = EE;
}

__global__ __launch_bounds__(256) void fill_kernel(const int* __restrict__ src,
                                                   const int* __restrict__ dst,
                                                   int* __restrict__ cursor,
                                                   int* __restrict__ sorted_src){
  int e = blockIdx.x * 256 + threadIdx.x;
  if (e < EE) {
    int pos = atomicAdd(&cursor[dst[e]], 1);
    sorted_src[pos] = src[e];
  }
}

// ---------------- per-node gather: o[n] = h[n] + sum_{s in N(n)} h[s] ----------------
// 8 nodes per 256-thread block; 32 lanes per node, float4 per lane (128 floats).
__global__ __launch_bounds__(256) void gather_kernel(const float4* __restrict__ h,
                                                     float4* __restrict__ o,
                                                     const int* __restrict__ row_start,
                                                     const int* __restrict__ sorted_src){
  int node = blockIdx.x * 8 + (threadIdx.x >> 5);
  int c = threadIdx.x & 31;
  if (node >= NN) return;
  float4 acc = h[(size_t)node * 32 + c];          // self term (eps=0)
  int beg = row_start[node], end = row_start[node + 1];
  for (int e = beg; e < end; ++e) {
    int s = sorted_src[e];
    float4 v = h[(size_t)s * 32 + c];
    acc.x += v.x; acc.y += v.y; acc.z += v.z; acc.w += v.w;
  }
  o[(size_t)node * 32 + c] = acc;
}

// ---------------- fused Linear + BN(eval) + ReLU ----------------
__global__ __launch_bounds__(256) void mlp_kernel(
    const float* __restrict__ X, float* __restrict__ O,
    const float* __restrict__ W, const float* __restrict__ bias,
    const float* __restrict__ gamma, const float* __restrict__ beta,
    const float* __restrict__ mean, const float* __restrict__ var)
{
  __shared__ float Wt[32][DD];            // k-tile of W (rows k, cols j)
  __shared__ float Xs[MROWS][DD + 4];     // pad keeps float4 align, shifts banks
  __shared__ float scale_s[DD], shift_s[DD];

  const int tid = threadIdx.x;
  if (tid < DD) {
    float s = gamma[tid] * rsqrtf(var[tid] + BN_EPS);
    scale_s[tid] = s;
    shift_s[tid] = (bias[tid] - mean[tid]) * s + beta[tid];
  }
  const int r0 = blockIdx.x * MROWS;
  for (int t = tid; t < MROWS * 32; t += 256) {
    int row = t >> 5, c4 = t & 31;
    *(float4*)&Xs[row][c4 * 4] = *(const float4*)(X + (size_t)(r0 + row) * DD + c4 * 4);
  }

  const int rg = tid >> 5, cg = tid & 31;   // 8 row-groups x 32 col-groups
  float acc[4][4];
  #pragma unroll
  for (int i = 0; i < 4; ++i)
    #pragma unroll
    for (int j = 0; j < 4; ++j) acc[i][j] = 0.f;

  for (int kt = 0; kt < DD / 32; ++kt) {
    __syncthreads();   // protects Wt reuse (and covers Xs/scale on kt=0)
    for (int t = tid; t < 32 * 32; t += 256) {
      int row = t >> 5, c4 = t & 31;
      *(float4*)&Wt[row][c4 * 4] =
          *(const float4*)(W + (size_t)(kt * 32 + row) * DD + c4 * 4);
    }
    __syncthreads();
    #pragma unroll
    for (int kk = 0; kk < 32; ++kk) {
      const int k = kt * 32 + kk;
      float4 w = *(float4*)&Wt[kk][cg * 4];
      float x0 = Xs[rg*4+0][k];
      float x1 = Xs[rg*4+1][k];
      float x2 = Xs[rg*4+2][k];
      float x3 = Xs[rg*4+3][k];
      acc[0][0] += x0*w.x; acc[0][1] += x0*w.y; acc[0][2] += x0*w.z; acc[0][3] += x0*w.w;
      acc[1][0] += x1*w.x; acc[1][1] += x1*w.y; acc[1][2] += x1*w.z; acc[1][3] += x1*w.w;
      acc[2][0] += x2*w.x; acc[2][1] += x2*w.y; acc[2][2] += x2*w.z; acc[2][3] += x2*w.w;
      acc[3][0] += x3*w.x; acc[3][1] += x3*w.y; acc[3][2] += x3*w.z; acc[3][3] += x3*w.w;
    }
  }

  float sc[4], sh[4];
  #pragma unroll
  for (int j = 0; j < 4; ++j) { sc[j] = scale_s[cg*4+j]; sh[j] = shift_s[cg*4+j]; }
  #pragma unroll
  for (int i = 0; i < 4; ++i) {
    float4 o;
    o.x = fmaxf(acc[i][0]*sc[0]+sh[0], 0.f);
    o.y = fmaxf(acc[i][1]*sc[1]+sh[1], 0.f);
    o.z = fmaxf(acc[i][2]*sc[2]+sh[2], 0.f);
    o.w = fmaxf(acc[i][3]*sc[3]+sh[3], 0.f);
    *(float4*)(O + (size_t)(r0 + rg*4 + i) * DD + cg*4) = o;
  }
}

// ---------------- segmented max-pool (batch is sorted) + classify ----------------

// one block per graph; binary-search node range; 8 row-groups x 32 cols
__global__ __launch_bounds__(256) void pool_seg_kernel(const float4* __restrict__ h,
    const int* __restrict__ batch, float4* __restrict__ pooled){
  __shared__ float4 red[256];
  __shared__ int range[2];
  const int g = blockIdx.x, tid = threadIdx.x;
  if (tid < 2) {
    int target = g + tid;            // lower_bound(batch, target)
    int lo = 0, hi = NN;
    while (lo < hi) { int mid = (lo + hi) >> 1; if (batch[mid] < target) lo = mid + 1; else hi = mid; }
    range[tid] = lo;
  }
  __syncthreads();
  const int beg = range[0], end = range[1];
  const int rg = tid >> 5, c = tid & 31;
  float4 mx = make_float4(0.f, 0.f, 0.f, 0.f);   // identity ok: h post-ReLU >= 0
  for (int n = beg + rg; n < end; n += 8) {
    float4 v = h[(size_t)n * 32 + c];
    mx.x = fmaxf(mx.x, v.x); mx.y = fmaxf(mx.y, v.y);
    mx.z = fmaxf(mx.z, v.z); mx.w = fmaxf(mx.w, v.w);
  }
  red[tid] = mx;
  __syncthreads();
  #pragma unroll
  for (int off = 4; off > 0; off >>= 1) {
    if (rg < off) {
      float4 o = red[(rg + off) * 32 + c];
      float4 m = red[tid];
      m.x = fmaxf(m.x, o.x); m.y = fmaxf(m.y, o.y);
      m.z = fmaxf(m.z, o.z); m.w = fmaxf(m.w, o.w);
      red[tid] = m;
    }
    __syncthreads();
  }
  if (rg == 0) pooled[g * 32 + c] = red[c];
}

__global__ __launch_bounds__(64) void classify_kernel(const float* __restrict__ pooled,
    const float* __restrict__ lw, const float* __restrict__ lb, float* __restrict__ out){
  int g = blockIdx.x, lane = threadIdx.x;
  float x0 = pooled[g*DD + lane];
  float x1 = pooled[g*DD + 64 + lane];
  float4 wA = *(const float4*)(lw + lane*4);        // lin_W[lane][0..3]
  float4 wB = *(const float4*)(lw + (lane+64)*4);   // lin_W[lane+64][0..3]
  float a0 = x0*wA.x + x1*wB.x;
  float a1 = x0*wA.y + x1*wB.y;
  float a2 = x0*wA.z + x1*wB.z;
  float a3 = x0*wA.w + x1*wB.w;
  #pragma unroll
  for (int off = 32; off > 0; off >>= 1) {
    a0 += __shfl_down(a0, off);
    a1 += __shfl_down(a1, off);
    a2 += __shfl_down(a2, off);
    a3 += __shfl_down(a3, off);
  }
  if (lane == 0) {
    float l0 = a0 + lb[0];
    float l1 = a1 + lb[1];
    float l2 = a2 + lb[2];
    float l3 = a3 + lb[3];
    float m = fmaxf(fmaxf(l0,l1), fmaxf(l2,l3));
    float s = expf(l0-m)+expf(l1-m)+expf(l2-m)+expf(l3-m);
    float lse = logf(s) + m;
    out[g*4+0] = l0 - lse;
    out[g*4+1] = l1 - lse;
    out[g*4+2] = l2 - lse;
    out[g*4+3] = l3 - lse;
  }
}

extern "C" void kernel_launch(void* const* d_in, const int* in_sizes, int n_in,
                              void* d_out, int out_size, void* d_ws, size_t ws_size,
                              hipStream_t stream) {
  const float* x     = (const float*)d_in[0];
  const int* ei      = (const int*)d_in[1];
  const int* batch   = (const int*)d_in[2];
  const float* Ws    = (const float*)d_in[3];
  const float* bs    = (const float*)d_in[4];
  const float* gammas= (const float*)d_in[5];
  const float* betas = (const float*)d_in[6];
  const float* means = (const float*)d_in[7];
  const float* vars  = (const float*)d_in[8];
  const float* lw    = (const float*)d_in[9];
  const float* lb    = (const float*)d_in[10];
  float* out = (float*)d_out;

  // workspace layout
  float* bufA   = (float*)d_ws;                         // N*D
  float* bufB   = bufA + (size_t)NN * DD;               // N*D
  float* pooled = bufB + (size_t)NN * DD;               // G*D
  int* deg        = (int*)(pooled + GG * DD);           // N (reused as cursor)
  int* row_start  = deg + NN;                           // N+1
  int* bsum       = row_start + NN + 1;                 // NBLK
  int* bofs       = bsum + NBLK;                        // NBLK
  int* sorted_src = bofs + NBLK + 2;                    // E  (keeps 16B align)

  const int* srcIdx = ei;
  const int* dstIdx = ei + EE;

  // ---- CSR build (once; graph is static across layers) ----
  hipMemsetAsync(deg, 0, NN * sizeof(int), stream);
  hist_kernel<<<(EE + 255)/256, 256, 0, stream>>>(dstIdx, deg);
  scan_blocksum<<<NBLK, 256, 0, stream>>>(deg, bsum);
  scan_bsums<<<1, 64, 0, stream>>>(bsum, bofs);
  scan_final<<<NBLK, 256, 0, stream>>>(deg, bofs, row_start, deg /*cursor*/);
  fill_kernel<<<(EE + 255)/256, 256, 0, stream>>>(srcIdx, dstIdx, deg, sorted_src);

  // ---- 3 GIN layers ----
  const float* hin = x;
  float* A = bufA;
  float* B = bufB;
  for (int l = 0; l < LLAYERS; ++l) {
    gather_kernel<<<(NN + 7)/8, 256, 0, stream>>>(
        (const float4*)hin, (float4*)B, row_start, sorted_src);
    const float* W0 = Ws + (size_t)(l*KLIN+0)*DD*DD;
    const float* W1 = Ws + (size_t)(l*KLIN+1)*DD*DD;
    int p0 = (l*KLIN+0)*DD, p1 = (l*KLIN+1)*DD;
    mlp_kernel<<<NN/MROWS, 256, 0, stream>>>(B, A,
        W0, bs+p0, gammas+p0, betas+p0, means+p0, vars+p0);
    mlp_kernel<<<NN/MROWS, 256, 0, stream>>>(A, B,
        W1, bs+p1, gammas+p1, betas+p1, means+p1, vars+p1);
    hin = B;                      // h now lives in B
    float* t = A; A = B; B = t;   // swap roles for next layer
  }

  pool_seg_kernel<<<GG, 256, 0, stream>>>((const float4*)hin, batch, (float4*)pooled);
  classify_kernel<<<GG, 64, 0, stream>>>(pooled, lw, lb, out);
}

// Round 6
// 1322.759 us; speedup vs baseline: 12.8049x; 1.2019x over previous
//
#include <hip/hip_runtime.h>
#include <stdint.h>

#define NN 100000
#define EE 3200000
#define DD 128
#define GG 64
#define CC 4
#define LLAYERS 3
#define KLIN 2
#define BN_EPS 1e-5f
#define MROWS 32

#define BSH 8                                   // 256 nodes per bucket
#define NB ((NN + 255) >> BSH)                  // 391 buckets
#define CHUNK3 8192
#define NBLK3 ((EE + CHUNK3 - 1) / CHUNK3)      // 391
#define STAGE_CAP 10240                         // mean 8192, sigma ~90 -> huge margin

// ---------------- bucketed CSR build (counting sort by dst) ----------------

// per-block LDS bucket histogram -> one global add per (block,bucket)
__global__ __launch_bounds__(256) void bucket_hist(const int* __restrict__ dst,
                                                   int* __restrict__ bcount){
  __shared__ int lh[NB];
  for (int i = threadIdx.x; i < NB; i += 256) lh[i] = 0;
  __syncthreads();
  int b0 = blockIdx.x * CHUNK3;
  int bend = min(b0 + CHUNK3, EE);
  for (int i = b0 + threadIdx.x; i < bend; i += 256)
    atomicAdd(&lh[dst[i] >> BSH], 1);
  __syncthreads();
  for (int i = threadIdx.x; i < NB; i += 256)
    if (lh[i]) atomicAdd(&bcount[i], lh[i]);
}

// exclusive scan over NB bucket counts; init global cursors; row_start[NN]
__global__ __launch_bounds__(512) void bucket_scan(const int* __restrict__ bcount,
                                                   int* __restrict__ bofs,
                                                   int* __restrict__ gcur,
                                                   int* __restrict__ row_start){
  __shared__ int s[512];
  int t = threadIdx.x;
  int v = (t < NB) ? bcount[t] : 0;
  s[t] = v; __syncthreads();
  for (int off = 1; off < 512; off <<= 1) {
    int u = (t >= off) ? s[t - off] : 0;
    __syncthreads();
    s[t] += u;
    __syncthreads();
  }
  if (t < NB) { int e = s[t] - v; bofs[t] = e; gcur[t] = e; }
  if (t == 0) row_start[NN] = EE;
}

// scatter edges into bucket-contiguous record regions (src, local dst)
__global__ __launch_bounds__(256) void bucket_scatter(const int* __restrict__ src,
                                                      const int* __restrict__ dst,
                                                      int* __restrict__ gcur,
                                                      int2* __restrict__ rec){
  __shared__ int lh[NB];
  __shared__ int lbase[NB];
  int b0 = blockIdx.x * CHUNK3;
  int bend = min(b0 + CHUNK3, EE);
  for (int i = threadIdx.x; i < NB; i += 256) lh[i] = 0;
  __syncthreads();
  for (int i = b0 + threadIdx.x; i < bend; i += 256)
    atomicAdd(&lh[dst[i] >> BSH], 1);
  __syncthreads();
  for (int i = threadIdx.x; i < NB; i += 256) {
    int c = lh[i];
    lbase[i] = c ? atomicAdd(&gcur[i], c) : 0;
    lh[i] = 0;   // reuse as local cursor (same-thread order: read above, then reset)
  }
  __syncthreads();
  for (int i = b0 + threadIdx.x; i < bend; i += 256) {
    int d = dst[i];
    int bk = d >> BSH;
    int pos = lbase[bk] + atomicAdd(&lh[bk], 1);
    rec[pos] = make_int2(src[i], d & ((1 << BSH) - 1));
  }
}

// per-bucket local counting sort in LDS -> coalesced sorted_src + row_start
__global__ __launch_bounds__(256) void bucket_emit(const int2* __restrict__ rec,
                                                   const int* __restrict__ bofs,
                                                   const int* __restrict__ bcount,
                                                   int* __restrict__ row_start,
                                                   int* __restrict__ sorted_src){
  __shared__ int cnt[256];
  __shared__ int ofs[256];
  __shared__ int stage[STAGE_CAP];
  const int b = blockIdx.x, t = threadIdx.x;
  const int nodebase = b << BSH;
  const int nlocal = min(256, NN - nodebase);
  const int ebeg = bofs[b];
  const int ecnt = bcount[b];
  cnt[t] = 0;
  __syncthreads();
  for (int i = t; i < ecnt; i += 256) {
    int2 r = rec[ebeg + i];
    atomicAdd(&cnt[r.y], 1);
  }
  __syncthreads();
  int v = cnt[t];
  ofs[t] = v;
  __syncthreads();
  for (int off = 1; off < 256; off <<= 1) {
    int u = (t >= off) ? ofs[t - off] : 0;
    __syncthreads();
    ofs[t] += u;
    __syncthreads();
  }
  int excl = ofs[t] - v;
  if (t < nlocal) row_start[nodebase + t] = ebeg + excl;
  cnt[t] = excl;   // cursor
  __syncthreads();
  for (int i = t; i < ecnt; i += 256) {
    int2 r = rec[ebeg + i];
    int pos = atomicAdd(&cnt[r.y], 1);
    if (pos < STAGE_CAP) stage[pos] = r.x;
    else sorted_src[ebeg + pos] = r.x;   // overflow fallback (statistically never)
  }
  __syncthreads();
  int lim = min(ecnt, STAGE_CAP);
  for (int i = t; i < lim; i += 256)
    sorted_src[ebeg + i] = stage[i];
}

// ---------------- per-node gather: o[n] = h[n] + sum_{s in N(n)} h[s] ----------------
__global__ __launch_bounds__(256) void gather_kernel(const float4* __restrict__ h,
                                                     float4* __restrict__ o,
                                                     const int* __restrict__ row_start,
                                                     const int* __restrict__ sorted_src){
  int node = blockIdx.x * 8 + (threadIdx.x >> 5);
  int c = threadIdx.x & 31;
  if (node >= NN) return;
  float4 acc = h[(size_t)node * 32 + c];          // self term (eps=0)
  int beg = row_start[node], end = row_start[node + 1];
  for (int e = beg; e < end; ++e) {
    int s = sorted_src[e];
    float4 v = h[(size_t)s * 32 + c];
    acc.x += v.x; acc.y += v.y; acc.z += v.z; acc.w += v.w;
  }
  o[(size_t)node * 32 + c] = acc;
}

// ---------------- fused Linear + BN(eval) + ReLU ----------------
__global__ __launch_bounds__(256) void mlp_kernel(
    const float* __restrict__ X, float* __restrict__ O,
    const float* __restrict__ W, const float* __restrict__ bias,
    const float* __restrict__ gamma, const float* __restrict__ beta,
    const float* __restrict__ mean, const float* __restrict__ var)
{
  __shared__ float Wt[32][DD];            // k-tile of W (rows k, cols j)
  __shared__ float Xs[MROWS][DD + 4];     // pad keeps float4 align, shifts banks
  __shared__ float scale_s[DD], shift_s[DD];

  const int tid = threadIdx.x;
  if (tid < DD) {
    float s = gamma[tid] * rsqrtf(var[tid] + BN_EPS);
    scale_s[tid] = s;
    shift_s[tid] = (bias[tid] - mean[tid]) * s + beta[tid];
  }
  const int r0 = blockIdx.x * MROWS;
  for (int t = tid; t < MROWS * 32; t += 256) {
    int row = t >> 5, c4 = t & 31;
    *(float4*)&Xs[row][c4 * 4] = *(const float4*)(X + (size_t)(r0 + row) * DD + c4 * 4);
  }

  const int rg = tid >> 5, cg = tid & 31;   // 8 row-groups x 32 col-groups
  float acc[4][4];
  #pragma unroll
  for (int i = 0; i < 4; ++i)
    #pragma unroll
    for (int j = 0; j < 4; ++j) acc[i][j] = 0.f;

  for (int kt = 0; kt < DD / 32; ++kt) {
    __syncthreads();   // protects Wt reuse (and covers Xs/scale on kt=0)
    for (int t = tid; t < 32 * 32; t += 256) {
      int row = t >> 5, c4 = t & 31;
      *(float4*)&Wt[row][c4 * 4] =
          *(const float4*)(W + (size_t)(kt * 32 + row) * DD + c4 * 4);
    }
    __syncthreads();
    #pragma unroll
    for (int kk = 0; kk < 32; ++kk) {
      const int k = kt * 32 + kk;
      float4 w = *(float4*)&Wt[kk][cg * 4];
      float x0 = Xs[rg*4+0][k];
      float x1 = Xs[rg*4+1][k];
      float x2 = Xs[rg*4+2][k];
      float x3 = Xs[rg*4+3][k];
      acc[0][0] += x0*w.x; acc[0][1] += x0*w.y; acc[0][2] += x0*w.z; acc[0][3] += x0*w.w;
      acc[1][0] += x1*w.x; acc[1][1] += x1*w.y; acc[1][2] += x1*w.z; acc[1][3] += x1*w.w;
      acc[2][0] += x2*w.x; acc[2][1] += x2*w.y; acc[2][2] += x2*w.z; acc[2][3] += x2*w.w;
      acc[3][0] += x3*w.x; acc[3][1] += x3*w.y; acc[3][2] += x3*w.z; acc[3][3] += x3*w.w;
    }
  }

  float sc[4], sh[4];
  #pragma unroll
  for (int j = 0; j < 4; ++j) { sc[j] = scale_s[cg*4+j]; sh[j] = shift_s[cg*4+j]; }
  #pragma unroll
  for (int i = 0; i < 4; ++i) {
    float4 o;
    o.x = fmaxf(acc[i][0]*sc[0]+sh[0], 0.f);
    o.y = fmaxf(acc[i][1]*sc[1]+sh[1], 0.f);
    o.z = fmaxf(acc[i][2]*sc[2]+sh[2], 0.f);
    o.w = fmaxf(acc[i][3]*sc[3]+sh[3], 0.f);
    *(float4*)(O + (size_t)(r0 + rg*4 + i) * DD + cg*4) = o;
  }
}

// ---------------- segmented max-pool (batch is sorted) + classify ----------------

__global__ __launch_bounds__(256) void pool_seg_kernel(const float4* __restrict__ h,
    const int* __restrict__ batch, float4* __restrict__ pooled){
  __shared__ float4 red[256];
  __shared__ int range[2];
  const int g = blockIdx.x, tid = threadIdx.x;
  if (tid < 2) {
    int target = g + tid;            // lower_bound(batch, target)
    int lo = 0, hi = NN;
    while (lo < hi) { int mid = (lo + hi) >> 1; if (batch[mid] < target) lo = mid + 1; else hi = mid; }
    range[tid] = lo;
  }
  __syncthreads();
  const int beg = range[0], end = range[1];
  const int rg = tid >> 5, c = tid & 31;
  float4 mx = make_float4(0.f, 0.f, 0.f, 0.f);   // identity ok: h post-ReLU >= 0
  for (int n = beg + rg; n < end; n += 8) {
    float4 v = h[(size_t)n * 32 + c];
    mx.x = fmaxf(mx.x, v.x); mx.y = fmaxf(mx.y, v.y);
    mx.z = fmaxf(mx.z, v.z); mx.w = fmaxf(mx.w, v.w);
  }
  red[tid] = mx;
  __syncthreads();
  #pragma unroll
  for (int off = 4; off > 0; off >>= 1) {
    if (rg < off) {
      float4 o = red[(rg + off) * 32 + c];
      float4 m = red[tid];
      m.x = fmaxf(m.x, o.x); m.y = fmaxf(m.y, o.y);
      m.z = fmaxf(m.z, o.z); m.w = fmaxf(m.w, o.w);
      red[tid] = m;
    }
    __syncthreads();
  }
  if (rg == 0) pooled[g * 32 + c] = red[c];
}

__global__ __launch_bounds__(64) void classify_kernel(const float* __restrict__ pooled,
    const float* __restrict__ lw, const float* __restrict__ lb, float* __restrict__ out){
  int g = blockIdx.x, lane = threadIdx.x;
  float x0 = pooled[g*DD + lane];
  float x1 = pooled[g*DD + 64 + lane];
  float4 wA = *(const float4*)(lw + lane*4);        // lin_W[lane][0..3]
  float4 wB = *(const float4*)(lw + (lane+64)*4);   // lin_W[lane+64][0..3]
  float a0 = x0*wA.x + x1*wB.x;
  float a1 = x0*wA.y + x1*wB.y;
  float a2 = x0*wA.z + x1*wB.z;
  float a3 = x0*wA.w + x1*wB.w;
  #pragma unroll
  for (int off = 32; off > 0; off >>= 1) {
    a0 += __shfl_down(a0, off);
    a1 += __shfl_down(a1, off);
    a2 += __shfl_down(a2, off);
    a3 += __shfl_down(a3, off);
  }
  if (lane == 0) {
    float l0 = a0 + lb[0];
    float l1 = a1 + lb[1];
    float l2 = a2 + lb[2];
    float l3 = a3 + lb[3];
    float m = fmaxf(fmaxf(l0,l1), fmaxf(l2,l3));
    float s = expf(l0-m)+expf(l1-m)+expf(l2-m)+expf(l3-m);
    float lse = logf(s) + m;
    out[g*4+0] = l0 - lse;
    out[g*4+1] = l1 - lse;
    out[g*4+2] = l2 - lse;
    out[g*4+3] = l3 - lse;
  }
}

extern "C" void kernel_launch(void* const* d_in, const int* in_sizes, int n_in,
                              void* d_out, int out_size, void* d_ws, size_t ws_size,
                              hipStream_t stream) {
  const float* x     = (const float*)d_in[0];
  const int* ei      = (const int*)d_in[1];
  const int* batch   = (const int*)d_in[2];
  const float* Ws    = (const float*)d_in[3];
  const float* bs    = (const float*)d_in[4];
  const float* gammas= (const float*)d_in[5];
  const float* betas = (const float*)d_in[6];
  const float* means = (const float*)d_in[7];
  const float* vars  = (const float*)d_in[8];
  const float* lw    = (const float*)d_in[9];
  const float* lb    = (const float*)d_in[10];
  float* out = (float*)d_out;

  // workspace layout
  float* bufA   = (float*)d_ws;                         // N*D (also aliases rec during CSR build)
  float* bufB   = bufA + (size_t)NN * DD;               // N*D
  float* pooled = bufB + (size_t)NN * DD;               // G*D
  int* row_start  = (int*)(pooled + GG * DD);           // N+1
  int* bcount     = row_start + NN + 2;                 // NB
  int* bofs       = bcount + NB;                        // NB
  int* gcur       = bofs + NB;                          // NB
  int* sorted_src = gcur + NB + 3;                      // E (16B-aligned region start)
  int2* rec       = (int2*)bufA;                        // E records, dead before mlp0 writes bufA

  const int* srcIdx = ei;
  const int* dstIdx = ei + EE;

  // ---- CSR build (bucketed counting sort; graph static across layers) ----
  hipMemsetAsync(bcount, 0, NB * sizeof(int), stream);
  bucket_hist<<<NBLK3, 256, 0, stream>>>(dstIdx, bcount);
  bucket_scan<<<1, 512, 0, stream>>>(bcount, bofs, gcur, row_start);
  bucket_scatter<<<NBLK3, 256, 0, stream>>>(srcIdx, dstIdx, gcur, rec);
  bucket_emit<<<NB, 256, 0, stream>>>(rec, bofs, bcount, row_start, sorted_src);

  // ---- 3 GIN layers ----
  const float* hin = x;
  float* A = bufA;
  float* B = bufB;
  for (int l = 0; l < LLAYERS; ++l) {
    gather_kernel<<<(NN + 7)/8, 256, 0, stream>>>(
        (const float4*)hin, (float4*)B, row_start, sorted_src);
    const float* W0 = Ws + (size_t)(l*KLIN+0)*DD*DD;
    const float* W1 = Ws + (size_t)(l*KLIN+1)*DD*DD;
    int p0 = (l*KLIN+0)*DD, p1 = (l*KLIN+1)*DD;
    mlp_kernel<<<NN/MROWS, 256, 0, stream>>>(B, A,
        W0, bs+p0, gammas+p0, betas+p0, means+p0, vars+p0);
    mlp_kernel<<<NN/MROWS, 256, 0, stream>>>(A, B,
        W1, bs+p1, gammas+p1, betas+p1, means+p1, vars+p1);
    hin = B;                      // h now lives in B
    float* t = A; A = B; B = t;   // swap roles for next layer
  }

  pool_seg_kernel<<<GG, 256, 0, stream>>>((const float4*)hin, batch, (float4*)pooled);
  classify_kernel<<<GG, 64, 0, stream>>>(pooled, lw, lb, out);
}

// Round 7
// 770.536 us; speedup vs baseline: 21.9818x; 1.7167x over previous
//
#include <hip/hip_runtime.h>
#include <stdint.h>

#define NN 100000
#define EE 3200000
#define DD 128
#define GG 64
#define CC 4
#define LLAYERS 3
#define KLIN 2
#define BN_EPS 1e-5f

#define BSH 8                                   // 256 nodes per bucket
#define NB ((NN + 255) >> BSH)                  // 391 buckets
#define CHUNK3 8192
#define NBLK3 ((EE + CHUNK3 - 1) / CHUNK3)      // 391
#define STAGE_CAP 10240

typedef unsigned short u16;
typedef unsigned int u32;
typedef short bf16x8 __attribute__((ext_vector_type(8)));
typedef float f32x4 __attribute__((ext_vector_type(4)));

__device__ __forceinline__ float bflo(u32 u){ return __uint_as_float(u << 16); }
__device__ __forceinline__ float bfhi(u32 u){ return __uint_as_float(u & 0xffff0000u); }
__device__ __forceinline__ u16 f2bf(float f){
  u32 u = __float_as_uint(f);
  u32 r = u + 0x7fffu + ((u >> 16) & 1u);   // RNE
  return (u16)(r >> 16);
}

// ---------------- bucketed CSR build (counting sort by dst) ----------------

__global__ __launch_bounds__(256) void bucket_hist(const int* __restrict__ dst,
                                                   int* __restrict__ bcount){
  __shared__ int lh[NB];
  for (int i = threadIdx.x; i < NB; i += 256) lh[i] = 0;
  __syncthreads();
  int b0 = blockIdx.x * CHUNK3;
  int bend = min(b0 + CHUNK3, EE);
  for (int i = b0 + threadIdx.x; i < bend; i += 256)
    atomicAdd(&lh[dst[i] >> BSH], 1);
  __syncthreads();
  for (int i = threadIdx.x; i < NB; i += 256)
    if (lh[i]) atomicAdd(&bcount[i], lh[i]);
}

__global__ __launch_bounds__(512) void bucket_scan(const int* __restrict__ bcount,
                                                   int* __restrict__ bofs,
                                                   int* __restrict__ gcur,
                                                   int* __restrict__ row_start){
  __shared__ int s[512];
  int t = threadIdx.x;
  int v = (t < NB) ? bcount[t] : 0;
  s[t] = v; __syncthreads();
  for (int off = 1; off < 512; off <<= 1) {
    int u = (t >= off) ? s[t - off] : 0;
    __syncthreads();
    s[t] += u;
    __syncthreads();
  }
  if (t < NB) { int e = s[t] - v; bofs[t] = e; gcur[t] = e; }
  if (t == 0) row_start[NN] = EE;
}

__global__ __launch_bounds__(256) void bucket_scatter(const int* __restrict__ src,
                                                      const int* __restrict__ dst,
                                                      int* __restrict__ gcur,
                                                      int2* __restrict__ rec){
  __shared__ int lh[NB];
  __shared__ int lbase[NB];
  int b0 = blockIdx.x * CHUNK3;
  int bend = min(b0 + CHUNK3, EE);
  for (int i = threadIdx.x; i < NB; i += 256) lh[i] = 0;
  __syncthreads();
  for (int i = b0 + threadIdx.x; i < bend; i += 256)
    atomicAdd(&lh[dst[i] >> BSH], 1);
  __syncthreads();
  for (int i = threadIdx.x; i < NB; i += 256) {
    int c = lh[i];
    lbase[i] = c ? atomicAdd(&gcur[i], c) : 0;
    lh[i] = 0;
  }
  __syncthreads();
  for (int i = b0 + threadIdx.x; i < bend; i += 256) {
    int d = dst[i];
    int bk = d >> BSH;
    int pos = lbase[bk] + atomicAdd(&lh[bk], 1);
    rec[pos] = make_int2(src[i], d & ((1 << BSH) - 1));
  }
}

__global__ __launch_bounds__(256) void bucket_emit(const int2* __restrict__ rec,
                                                   const int* __restrict__ bofs,
                                                   const int* __restrict__ bcount,
                                                   int* __restrict__ row_start,
                                                   int* __restrict__ sorted_src){
  __shared__ int cnt[256];
  __shared__ int ofs[256];
  __shared__ int stage[STAGE_CAP];
  const int b = blockIdx.x, t = threadIdx.x;
  const int nodebase = b << BSH;
  const int nlocal = min(256, NN - nodebase);
  const int ebeg = bofs[b];
  const int ecnt = bcount[b];
  cnt[t] = 0;
  __syncthreads();
  for (int i = t; i < ecnt; i += 256) {
    int2 r = rec[ebeg + i];
    atomicAdd(&cnt[r.y], 1);
  }
  __syncthreads();
  int v = cnt[t];
  ofs[t] = v;
  __syncthreads();
  for (int off = 1; off < 256; off <<= 1) {
    int u = (t >= off) ? ofs[t - off] : 0;
    __syncthreads();
    ofs[t] += u;
    __syncthreads();
  }
  int excl = ofs[t] - v;
  if (t < nlocal) row_start[nodebase + t] = ebeg + excl;
  cnt[t] = excl;
  __syncthreads();
  for (int i = t; i < ecnt; i += 256) {
    int2 r = rec[ebeg + i];
    int pos = atomicAdd(&cnt[r.y], 1);
    if (pos < STAGE_CAP) stage[pos] = r.x;
    else sorted_src[ebeg + pos] = r.x;
  }
  __syncthreads();
  int lim = min(ecnt, STAGE_CAP);
  for (int i = t; i < lim; i += 256)
    sorted_src[ebeg + i] = stage[i];
}

// ---------------- prep: swizzle W -> MFMA B-fragment order (bf16), BN fold ----------------
// Wt[((ct*4+ks)*64+lane)*8+j] = bf16(W[ks*32+(lane>>4)*8+j][ct*16+(lane&15)])
__global__ __launch_bounds__(256) void prep_kernel(const float* __restrict__ Ws,
    const float* __restrict__ bs, const float* __restrict__ gammas,
    const float* __restrict__ betas, const float* __restrict__ means,
    const float* __restrict__ vars,
    u16* __restrict__ Wt6, float* __restrict__ scale6, float* __restrict__ shift6){
  const int s = blockIdx.x;   // sublayer 0..5
  const float* W = Ws + (size_t)s * DD * DD;
  u16* Wt = Wt6 + (size_t)s * DD * DD;
  const int t = threadIdx.x;
  if (t < DD) {
    float sc = gammas[s*DD+t] * rsqrtf(vars[s*DD+t] + BN_EPS);
    scale6[s*DD+t] = sc;
    shift6[s*DD+t] = (bs[s*DD+t] - means[s*DD+t]) * sc + betas[s*DD+t];
  }
  for (int f = t; f < DD*DD; f += 256) {
    int j = f & 7, lane = (f >> 3) & 63, ks = (f >> 9) & 3, ct = f >> 11;
    int k = ks*32 + (lane >> 4)*8 + j;
    int n = ct*16 + (lane & 15);
    Wt[f] = f2bf(W[k*DD + n]);
  }
}

// ---------------- cast x (f32) -> h (bf16) ----------------
__global__ __launch_bounds__(256) void cast_x_kernel(const float4* __restrict__ x,
                                                     uint4* __restrict__ h){
  int i = blockIdx.x * 256 + threadIdx.x;   // 8 f32 per thread
  if (i < NN*DD/8) {
    float4 a = x[2*i], b = x[2*i+1];
    uint4 o;
    o.x = (u32)f2bf(a.x) | ((u32)f2bf(a.y) << 16);
    o.y = (u32)f2bf(a.z) | ((u32)f2bf(a.w) << 16);
    o.z = (u32)f2bf(b.x) | ((u32)f2bf(b.y) << 16);
    o.w = (u32)f2bf(b.z) | ((u32)f2bf(b.w) << 16);
    h[i] = o;
  }
}

// ---------------- gather (bf16): o[n] = h[n] + sum_{s in N(n)} h[s] ----------------
// 16 nodes per block, 16 lanes per node, 8 bf16 (16B) per lane
__global__ __launch_bounds__(256) void gather_bf16(const u16* __restrict__ h,
    u16* __restrict__ o, const int* __restrict__ row_start,
    const int* __restrict__ sorted_src){
  const int node = blockIdx.x * 16 + (threadIdx.x >> 4);
  const int l16 = threadIdx.x & 15;
  const uint4* hp = (const uint4*)h;
  uint4 v = hp[(size_t)node * 16 + l16];
  float a0 = bflo(v.x), a1 = bfhi(v.x), a2 = bflo(v.y), a3 = bfhi(v.y);
  float a4 = bflo(v.z), a5 = bfhi(v.z), a6 = bflo(v.w), a7 = bfhi(v.w);
  const int beg = row_start[node], end = row_start[node + 1];
  for (int e = beg; e < end; ++e) {
    int s = sorted_src[e];
    uint4 u = hp[(size_t)s * 16 + l16];
    a0 += bflo(u.x); a1 += bfhi(u.x); a2 += bflo(u.y); a3 += bfhi(u.y);
    a4 += bflo(u.z); a5 += bfhi(u.z); a6 += bflo(u.w); a7 += bfhi(u.w);
  }
  uint4 w;
  w.x = (u32)f2bf(a0) | ((u32)f2bf(a1) << 16);
  w.y = (u32)f2bf(a2) | ((u32)f2bf(a3) << 16);
  w.z = (u32)f2bf(a4) | ((u32)f2bf(a5) << 16);
  w.w = (u32)f2bf(a6) | ((u32)f2bf(a7) << 16);
  ((uint4*)o)[(size_t)node * 16 + l16] = w;
}

// ---------------- MFMA MLP: O = relu(bn(X @ W)) in bf16 ----------------
// block = 4 waves; wave = 16 rows x 128 cols (8 col-tiles x 4 k-steps)
__global__ __launch_bounds__(256) void mlp_mfma(
    const u16* __restrict__ X, u16* __restrict__ O,
    const u16* __restrict__ Wt, const float* __restrict__ scale,
    const float* __restrict__ shift)
{
  const int tid = threadIdx.x;
  const int wave = tid >> 6, lane = tid & 63;
  const int ln15 = lane & 15, quad = lane >> 4;
  const int r0 = blockIdx.x * 64 + wave * 16;
  int row_a = r0 + ln15; if (row_a >= NN) row_a = NN - 1;   // clamp (masked at store)

  f32x4 acc[8];
  #pragma unroll
  for (int ct = 0; ct < 8; ++ct) acc[ct] = (f32x4){0.f, 0.f, 0.f, 0.f};

  #pragma unroll
  for (int ks = 0; ks < 4; ++ks) {
    // A[m=ln15][k = ks*32 + quad*8 + j]  -> contiguous 8 bf16
    bf16x8 af = *(const bf16x8*)(X + (size_t)row_a * DD + ks*32 + quad*8);
    #pragma unroll
    for (int ct = 0; ct < 8; ++ct) {
      bf16x8 bf = *(const bf16x8*)(Wt + (((ct*4 + ks)*64 + lane) << 3));
      acc[ct] = __builtin_amdgcn_mfma_f32_16x16x32_bf16(af, bf, acc[ct], 0, 0, 0);
    }
  }

  float sc[8], sh[8];
  #pragma unroll
  for (int ct = 0; ct < 8; ++ct) {
    sc[ct] = scale[ct*16 + ln15];
    sh[ct] = shift[ct*16 + ln15];
  }
  // C/D: row = r0 + quad*4 + reg, col = ct*16 + ln15
  #pragma unroll
  for (int reg = 0; reg < 4; ++reg) {
    int row = r0 + quad*4 + reg;
    if (row < NN) {
      #pragma unroll
      for (int ct = 0; ct < 8; ++ct) {
        float vv = fmaxf(acc[ct][reg] * sc[ct] + sh[ct], 0.f);
        O[(size_t)row * DD + ct*16 + ln15] = f2bf(vv);
      }
    }
  }
}

// ---------------- segmented max-pool (batch sorted) over bf16 h ----------------
__global__ __launch_bounds__(256) void pool_seg_bf16(const u16* __restrict__ h,
    const int* __restrict__ batch, float* __restrict__ pooled){
  __shared__ float red[256 * 8];
  __shared__ int range[2];
  const int g = blockIdx.x, tid = threadIdx.x;
  if (tid < 2) {
    int target = g + tid;
    int lo = 0, hi = NN;
    while (lo < hi) { int mid = (lo + hi) >> 1; if (batch[mid] < target) lo = mid + 1; else hi = mid; }
    range[tid] = lo;
  }
  __syncthreads();
  const int beg = range[0], end = range[1];
  const int rg = tid >> 4, l16 = tid & 15;
  const uint4* hp = (const uint4*)h;
  float m0=0.f,m1=0.f,m2=0.f,m3=0.f,m4=0.f,m5=0.f,m6=0.f,m7=0.f;  // h >= 0
  for (int n = beg + rg; n < end; n += 16) {
    uint4 u = hp[(size_t)n * 16 + l16];
    m0 = fmaxf(m0, bflo(u.x)); m1 = fmaxf(m1, bfhi(u.x));
    m2 = fmaxf(m2, bflo(u.y)); m3 = fmaxf(m3, bfhi(u.y));
    m4 = fmaxf(m4, bflo(u.z)); m5 = fmaxf(m5, bfhi(u.z));
    m6 = fmaxf(m6, bflo(u.w)); m7 = fmaxf(m7, bfhi(u.w));
  }
  float* r = &red[tid * 8];
  r[0]=m0; r[1]=m1; r[2]=m2; r[3]=m3; r[4]=m4; r[5]=m5; r[6]=m6; r[7]=m7;
  __syncthreads();
  #pragma unroll
  for (int off = 8; off > 0; off >>= 1) {
    if (rg < off) {
      float* o = &red[(tid + off*16) * 8];
      #pragma unroll
      for (int i = 0; i < 8; ++i) r[i] = fmaxf(r[i], o[i]);
    }
    __syncthreads();
  }
  if (rg == 0) {
    #pragma unroll
    for (int i = 0; i < 8; ++i) pooled[g*DD + l16*8 + i] = r[i];
  }
}

__global__ __launch_bounds__(64) void classify_kernel(const float* __restrict__ pooled,
    const float* __restrict__ lw, const float* __restrict__ lb, float* __restrict__ out){
  int g = blockIdx.x, lane = threadIdx.x;
  float x0 = pooled[g*DD + lane];
  float x1 = pooled[g*DD + 64 + lane];
  float4 wA = *(const float4*)(lw + lane*4);
  float4 wB = *(const float4*)(lw + (lane+64)*4);
  float a0 = x0*wA.x + x1*wB.x;
  float a1 = x0*wA.y + x1*wB.y;
  float a2 = x0*wA.z + x1*wB.z;
  float a3 = x0*wA.w + x1*wB.w;
  #pragma unroll
  for (int off = 32; off > 0; off >>= 1) {
    a0 += __shfl_down(a0, off);
    a1 += __shfl_down(a1, off);
    a2 += __shfl_down(a2, off);
    a3 += __shfl_down(a3, off);
  }
  if (lane == 0) {
    float l0 = a0 + lb[0];
    float l1 = a1 + lb[1];
    float l2 = a2 + lb[2];
    float l3 = a3 + lb[3];
    float m = fmaxf(fmaxf(l0,l1), fmaxf(l2,l3));
    float s = expf(l0-m)+expf(l1-m)+expf(l2-m)+expf(l3-m);
    float lse = logf(s) + m;
    out[g*4+0] = l0 - lse;
    out[g*4+1] = l1 - lse;
    out[g*4+2] = l2 - lse;
    out[g*4+3] = l3 - lse;
  }
}

extern "C" void kernel_launch(void* const* d_in, const int* in_sizes, int n_in,
                              void* d_out, int out_size, void* d_ws, size_t ws_size,
                              hipStream_t stream) {
  const float* x     = (const float*)d_in[0];
  const int* ei      = (const int*)d_in[1];
  const int* batch   = (const int*)d_in[2];
  const float* Ws    = (const float*)d_in[3];
  const float* bs    = (const float*)d_in[4];
  const float* gammas= (const float*)d_in[5];
  const float* betas = (const float*)d_in[6];
  const float* means = (const float*)d_in[7];
  const float* vars  = (const float*)d_in[8];
  const float* lw    = (const float*)d_in[9];
  const float* lb    = (const float*)d_in[10];
  float* out = (float*)d_out;

  // workspace layout
  u16* hA = (u16*)d_ws;                                 // N*D bf16 (aliased by rec in CSR build)
  u16* hB = hA + (size_t)NN * DD;                       // N*D bf16
  float* pooled = (float*)(hB + (size_t)NN * DD);       // G*D f32
  float* scale6 = pooled + GG * DD;                     // 6*D
  float* shift6 = scale6 + 6 * DD;                      // 6*D
  int* row_start  = (int*)(shift6 + 6 * DD);            // N+1
  int* bcount     = row_start + NN + 2;                 // NB
  int* bofs       = bcount + NB;                        // NB
  int* gcur       = bofs + NB;                          // NB
  int* sorted_src = gcur + NB + 3;                      // E
  u16* Wt6 = (u16*)(((uintptr_t)(sorted_src + EE) + 63) & ~(uintptr_t)63);  // 6*D*D bf16
  int2* rec = (int2*)hA;                                // E records (dead before cast_x)

  const int* srcIdx = ei;
  const int* dstIdx = ei + EE;

  // ---- CSR build ----
  hipMemsetAsync(bcount, 0, NB * sizeof(int), stream);
  bucket_hist<<<NBLK3, 256, 0, stream>>>(dstIdx, bcount);
  bucket_scan<<<1, 512, 0, stream>>>(bcount, bofs, gcur, row_start);
  bucket_scatter<<<NBLK3, 256, 0, stream>>>(srcIdx, dstIdx, gcur, rec);
  bucket_emit<<<NB, 256, 0, stream>>>(rec, bofs, bcount, row_start, sorted_src);

  // ---- prep (W swizzle + BN fold) and x cast ----
  prep_kernel<<<6, 256, 0, stream>>>(Ws, bs, gammas, betas, means, vars,
                                     Wt6, scale6, shift6);
  cast_x_kernel<<<(NN*DD/8 + 255)/256, 256, 0, stream>>>((const float4*)x, (uint4*)hA);

  // ---- 3 GIN layers ----
  u16* cur = hA;   // h
  u16* tmp = hB;
  const int mlp_grid = (NN + 63) / 64;
  for (int l = 0; l < LLAYERS; ++l) {
    gather_bf16<<<NN/16, 256, 0, stream>>>(cur, tmp, row_start, sorted_src);
    int s0 = l*KLIN + 0, s1 = l*KLIN + 1;
    mlp_mfma<<<mlp_grid, 256, 0, stream>>>(tmp, cur,
        Wt6 + (size_t)s0*DD*DD, scale6 + s0*DD, shift6 + s0*DD);
    mlp_mfma<<<mlp_grid, 256, 0, stream>>>(cur, tmp,
        Wt6 + (size_t)s1*DD*DD, scale6 + s1*DD, shift6 + s1*DD);
    u16* t = cur; cur = tmp; tmp = t;   // h now in cur
  }

  pool_seg_bf16<<<GG, 256, 0, stream>>>(cur, batch, pooled);
  classify_kernel<<<GG, 64, 0, stream>>>(pooled, lw, lb, out);
}